// Round 7
// baseline (289.587 us; speedup 1.0000x reference)
//
#include <hip/hip_runtime.h>
#include <math.h>

// Problem constants
constexpr int Bb = 2, Ss = 2048, Dd = 1024, Hh = 16, Kk = 16;
constexpr float DELTA = 0.02f;   // candidate margin (~30 sigma of bf16 approx error)

typedef __bf16 bf16x8 __attribute__((ext_vector_type(8)));
typedef __bf16 bf16x4 __attribute__((ext_vector_type(4)));
typedef float  f32x4  __attribute__((ext_vector_type(4)));

__device__ __forceinline__ void gld_lds16(const void* g, void* l) {
    __builtin_amdgcn_global_load_lds(
        (const __attribute__((address_space(1))) unsigned int*)g,
        (__attribute__((address_space(3))) unsigned int*)l, 16, 0, 0);
}

// ---------------------------------------------------------------------------
// Merged prep: bid<1024 -> float4 inits (Y=0, hbuf=0, qkvsel=0, imp=0,
// zbuf=bv, obuf=bo, cnt=0); 1024..5119 -> per-batch transpose x -> xbT
// AND pack x -> xb from the same tile (x read ONCE); bid>=5120 -> Ws1 T.
// ---------------------------------------------------------------------------
__global__ void __launch_bounds__(256) prep_kernel(
    const float* __restrict__ x, __bf16* __restrict__ xb,
    __bf16* __restrict__ xbT,
    float* __restrict__ imp, float* __restrict__ hbuf,
    float* __restrict__ qkvsel, int* __restrict__ ccount,
    const float* __restrict__ Ws1, __bf16* __restrict__ W1Th,
    const float* __restrict__ bv, const float* __restrict__ bo,
    float* __restrict__ Y, float* __restrict__ zbuf,
    float* __restrict__ obuf, int* __restrict__ cnt)
{
    __shared__ float tile[32][33];
    const int bid = blockIdx.x;
    const int t   = threadIdx.x;

    if (bid < 1024) {
        int i = bid * 256 + t;                       // 0..262143
        float4 z4 = {0.f, 0.f, 0.f, 0.f};
        if (i < 131072) ((float4*)Y)[i] = z4;
        if (i < 16384)  ((float4*)hbuf)[i] = z4;
        if (i < 24576)  ((float4*)qkvsel)[i] = z4;
        if (i < 8192)   ((float4*)zbuf)[i] = ((const float4*)bv)[i & 255];
        if (i < 8192)   ((float4*)obuf)[i] = ((const float4*)bo)[i & 255];
        if (i < 1024)   ((float4*)imp)[i] = z4;
        if (i < Bb)     ccount[i] = 0;
        if (i < 8)      cnt[i] = 0;
        return;
    }
    if (bid < 5120) {
        // transpose + pack: xbT[b][c][r] = x[b][r][c]; xb = bf16(x)
        int tid = bid - 1024;          // 0..4095, 2048 tiles per b
        int b   = tid >> 11;
        int rem = tid & 2047;
        int rt  = rem >> 5;            // 64 row-tiles (2048/32)
        int ct  = rem & 31;            // 32 col-tiles (1024/32)
        int tx = t & 31, ty = t >> 5;
        const float* xp = x + (size_t)b * Ss * Dd;
        __bf16* xbp = xb + (size_t)b * Ss * Dd;
        #pragma unroll
        for (int i2 = 0; i2 < 32; i2 += 8) {
            float v = xp[(size_t)(rt * 32 + ty + i2) * 1024 + ct * 32 + tx];
            tile[ty + i2][tx] = v;
            xbp[(size_t)(rt * 32 + ty + i2) * 1024 + ct * 32 + tx] = (__bf16)v;
        }
        __syncthreads();
        __bf16* xT = xbT + (size_t)b * Dd * Ss;
        #pragma unroll
        for (int i2 = 0; i2 < 32; i2 += 8)
            xT[(size_t)(ct * 32 + ty + i2) * 2048 + rt * 32 + tx] = (__bf16)tile[tx][ty + i2];
        return;
    }
    {
        int tid = bid - 5120;          // 0..511
        int n0 = (tid & 15) * 32;
        int k0 = (tid >> 4) * 32;
        int tx = t & 31, ty = t >> 5;
        #pragma unroll
        for (int i2 = 0; i2 < 32; i2 += 8)
            tile[ty + i2][tx] = Ws1[(size_t)(k0 + ty + i2) * 512 + n0 + tx];
        __syncthreads();
        #pragma unroll
        for (int i2 = 0; i2 < 32; i2 += 8)
            W1Th[(size_t)(n0 + ty + i2) * 1024 + k0 + tx] = (__bf16)tile[tx][ty + i2];
    }
}

// ---------------------------------------------------------------------------
// FUSED: indexer GEMM (256 blocks) + FAST topk run by the last-arriving
// block per batch (R5-verified fence protocol). topk: wave-0 argmax over
// LDS, no syncthreads in the 16-iteration loop. Grid (4 cb, 64 mtiles).
// ---------------------------------------------------------------------------
__global__ void __launch_bounds__(256) gemm_ind_topk(
    const __bf16* __restrict__ xb, const __bf16* __restrict__ W1Th,
    const float* __restrict__ bs1, const float* __restrict__ Ws2,
    float* __restrict__ imp, int* __restrict__ cnt,
    int* __restrict__ cand_idx, int* __restrict__ ccount)
{
    __shared__ __bf16 As[64 * 64];
    __shared__ __bf16 Bs[128 * 64];
    __shared__ float vals[2048];
    __shared__ float thr_s;
    __shared__ int   cnt_s;
    __shared__ int   lastf;

    const int cb   = blockIdx.x;
    const int bm   = blockIdx.y * 64;
    const int t    = threadIdx.x;
    const int wave = t >> 6;
    const int lane = t & 63;
    const int wm   = (wave & 1) * 32;
    const int wn   = (wave >> 1) * 64;
    const int fr   = lane & 15;
    const int fq   = lane >> 4;
    const int K    = Dd;

    const __bf16* BT = W1Th + (size_t)cb * 128 * 1024;

    f32x4 acc[2][4] = {};

    for (int k0 = 0; k0 < K; k0 += 64) {
        #pragma unroll
        for (int l = 0; l < 2; ++l) {
            int c = l * 256 + t;
            int row = c >> 3, seg = (c & 7) ^ (row & 7);
            gld_lds16(xb + (size_t)(bm + row) * K + k0 + seg * 8,
                      As + (size_t)(l * 256 + wave * 64) * 8);
        }
        #pragma unroll
        for (int l = 0; l < 4; ++l) {
            int c = l * 256 + t;
            int row = c >> 3, seg = (c & 7) ^ (row & 7);
            gld_lds16(BT + (size_t)row * K + k0 + seg * 8,
                      Bs + (size_t)(l * 256 + wave * 64) * 8);
        }
        __syncthreads();
        #pragma unroll
        for (int s = 0; s < 2; ++s) {
            bf16x8 af[2], bf[4];
            #pragma unroll
            for (int i = 0; i < 2; ++i) {
                int row = wm + i * 16 + fr;
                af[i] = *(const bf16x8*)(As + row * 64 + (((s * 4 + fq) ^ (row & 7)) * 8));
            }
            #pragma unroll
            for (int j = 0; j < 4; ++j) {
                int row = wn + j * 16 + fr;
                bf[j] = *(const bf16x8*)(Bs + row * 64 + (((s * 4 + fq) ^ (row & 7)) * 8));
            }
            #pragma unroll
            for (int i = 0; i < 2; ++i)
                #pragma unroll
                for (int j = 0; j < 4; ++j)
                    acc[i][j] = __builtin_amdgcn_mfma_f32_16x16x32_bf16(af[i], bf[j], acc[i][j], 0, 0, 0);
        }
        __syncthreads();
    }

    const int cr = (lane >> 4) * 4;
    const int cc = lane & 15;
    float bb[4], w2[4];
    #pragma unroll
    for (int j = 0; j < 4; ++j) {
        int col = cb * 128 + wn + j * 16 + cc;
        bb[j] = bs1[col];
        w2[j] = Ws2[col];
    }
    #pragma unroll
    for (int i = 0; i < 2; ++i) {
        #pragma unroll
        for (int r = 0; r < 4; ++r) {
            float vsum = 0.f;
            #pragma unroll
            for (int j = 0; j < 4; ++j)
                vsum += fmaxf(acc[i][j][r] + bb[j], 0.f) * w2[j];
            #pragma unroll
            for (int off = 8; off > 0; off >>= 1)
                vsum += __shfl_xor(vsum, off, 16);
            if (cc == 0)
                atomicAdd(imp + (bm + wm + i * 16 + cr + r), vsum);
        }
    }

    // ---- last-block-per-batch: fast top-16 + threshold band ----
    __threadfence();
    const int bq = blockIdx.y >> 5;                 // 32 row-tiles per batch
    if (t == 0) lastf = (atomicAdd(&cnt[bq], 1) == 127);
    __syncthreads();
    if (!lastf) return;
    __threadfence();

    #pragma unroll
    for (int e = 0; e < 8; ++e)
        vals[t + 256 * e] = imp[bq * Ss + t + 256 * e];
    __syncthreads();

    if (t < 64) {
        const int base = t * 32;
        for (int it = 0; it < Kk; ++it) {
            float best = -1e30f; int bidx = 0x7fffffff;
            #pragma unroll 8
            for (int j = 0; j < 32; ++j) {
                float v = vals[base + j];
                if (v > best) { best = v; bidx = base + j; }
            }
            #pragma unroll
            for (int off = 32; off > 0; off >>= 1) {
                float ov = __shfl_xor(best, off, 64);
                int   oi = __shfl_xor(bidx, off, 64);
                if (ov > best || (ov == best && oi < bidx)) { best = ov; bidx = oi; }
            }
            if (t == 0) {
                cand_idx[bq * 64 + it] = bidx;
                vals[bidx] = -1e30f;
                if (it == Kk - 1) { thr_s = best - DELTA; cnt_s = Kk; }
            }
        }
    }
    __syncthreads();

    float thr = thr_s;
    #pragma unroll
    for (int e = 0; e < 8; ++e) {
        if (vals[t + 256 * e] > thr) {
            int p = atomicAdd(&cnt_s, 1);
            if (p < 64) cand_idx[bq * 64 + p] = t + 256 * e;
        }
    }
    __syncthreads();
    if (t == 0) ccount[bq] = min(cnt_s, 64);
}

// ---------------------------------------------------------------------------
// Exact f32 rescore, phase 1 (unchanged, proven). NO trailing fence.
// ---------------------------------------------------------------------------
__global__ void __launch_bounds__(256) rescore_h(
    const float* __restrict__ x, const float* __restrict__ Ws1,
    const int* __restrict__ cand_idx, const int* __restrict__ ccount,
    float* __restrict__ hbuf)
{
    const int c = blockIdx.x, kc = blockIdx.y, b = blockIdx.z;
    if (c >= ccount[b]) return;
    const int row = cand_idx[b * 64 + c];
    const int t = threadIdx.x;
    const int k0 = kc * 64;

    __shared__ float xs[64];
    if (t < 16)
        ((float4*)xs)[t] = ((const float4*)(x + ((size_t)(b * Ss + row)) * Dd + k0))[t];
    __syncthreads();

    float a0 = 0.f, a1 = 0.f;
    const float* W = Ws1 + (size_t)k0 * 512;
    #pragma unroll 16
    for (int kk = 0; kk < 64; ++kk) {
        float xv = xs[kk];
        a0 = fmaf(xv, W[kk * 512 + t], a0);
        a1 = fmaf(xv, W[kk * 512 + t + 256], a1);
    }
    float* hb = hbuf + ((size_t)(b * 64 + c)) * 512;
    atomicAdd(hb + t, a0);
    atomicAdd(hb + t + 256, a1);
}

// ---------------------------------------------------------------------------
// MERGED rescore phase-2 + final selection (unchanged, proven R6).
// ---------------------------------------------------------------------------
__global__ void __launch_bounds__(256) rescore_fin_sel(
    const float* __restrict__ hbuf, const float* __restrict__ bs1,
    const float* __restrict__ Ws2, const int* __restrict__ cand_idx,
    const int* __restrict__ ccount, int* __restrict__ sel_idx)
{
    const int b = blockIdx.x;
    const int t = threadIdx.x;
    __shared__ float czv[64];
    __shared__ int   cidx[64];
    const int cntb = ccount[b];

    {
        const int cc = t >> 2, part = t & 3;
        const float* hb = hbuf + ((size_t)(b * 64 + cc)) * 512;
        float z = 0.f;
        const int j0 = part * 128;
        for (int j = j0; j < j0 + 128; ++j)
            z += fmaxf(hb[j] + bs1[j], 0.f) * Ws2[j];
        z += __shfl_xor(z, 1, 4);
        z += __shfl_xor(z, 2, 4);
        if (part == 0) { czv[cc] = z; cidx[cc] = cand_idx[b * 64 + cc]; }
    }
    __syncthreads();

    if (t < 64) {
        float val = (t < cntb) ? czv[t] : -1e30f;
        int   row = (t < cntb) ? cidx[t] : 0x7fffffff;
        for (int it = 0; it < Kk; ++it) {
            float bv = val; int br = row;
            #pragma unroll
            for (int off = 1; off < 64; off <<= 1) {
                float ov = __shfl_xor(bv, off, 64);
                int   orw = __shfl_xor(br, off, 64);
                if (ov > bv || (ov == bv && orw < br)) { bv = ov; br = orw; }
            }
            if (row == br) val = -1e30f;
            if (t == 0) sel_idx[b * Kk + it] = br;
        }
    }
}

// ---------------------------------------------------------------------------
// Exact f32 projections of the 32 selected rows (unchanged, proven).
// Grid (8 coltiles, 3 mats, 8 kchunks).
// ---------------------------------------------------------------------------
__global__ void __launch_bounds__(256) proj_sel(
    const float* __restrict__ x,
    const float* __restrict__ Wq, const float* __restrict__ Wk,
    const float* __restrict__ Wv,
    const int* __restrict__ sel_idx, float* __restrict__ qkvsel)
{
    const int cx = blockIdx.x;
    const int m  = blockIdx.y;
    const int kc = blockIdx.z;
    const int t  = threadIdx.x;
    __shared__ int   sj[32];
    __shared__ float xs[32][128];

    if (t < 32) sj[t] = sel_idx[t];
    __syncthreads();

    const int k0 = kc * 128;
    #pragma unroll
    for (int l = 0; l < 4; ++l) {
        int c = l * 256 + t;
        int r = c >> 5, kq = c & 31;
        int b = r >> 4;
        float4 v = *(const float4*)(x + ((size_t)(b * Ss + sj[r])) * Dd + k0 + kq * 4);
        *(float4*)&xs[r][kq * 4] = v;
    }
    __syncthreads();

    const float* W = (m == 0) ? Wq : (m == 1) ? Wk : Wv;
    const int col = cx * 128 + (t & 127);
    const int rh  = t >> 7;
    float acc[16] = {};
    #pragma unroll 4
    for (int kk = 0; kk < 128; ++kk) {
        float wv = W[(size_t)(k0 + kk) * 1024 + col];
        #pragma unroll
        for (int r = 0; r < 16; ++r)
            acc[r] = fmaf(xs[rh * 16 + r][kk], wv, acc[r]);
    }
    #pragma unroll
    for (int r = 0; r < 16; ++r)
        atomicAdd(qkvsel + (size_t)(m * 32 + rh * 16 + r) * 1024 + col, acc[r]);
}

// ---------------------------------------------------------------------------
// Build the algebraic operands (unchanged, proven). Grid (8,16,2).
// ---------------------------------------------------------------------------
__global__ void __launch_bounds__(256) build_cdvo(
    const float* __restrict__ Wq, const float* __restrict__ Wk,
    const float* __restrict__ Wo,
    const float* __restrict__ bq, const float* __restrict__ bk,
    const float* __restrict__ bv,
    const float* __restrict__ qkvsel, float* __restrict__ beta,
    __bf16* __restrict__ ET, __bf16* __restrict__ VoT)
{
    const int nx = blockIdx.x;
    const int h  = blockIdx.y;
    const int b  = blockIdx.z;
    const int t  = threadIdx.x;
    __shared__ float qs[16][64], ks[16][64], vs[16][64];
    __shared__ float wt[128][65];

    #pragma unroll
    for (int l = 0; l < 12; ++l) {
        int c = l * 256 + t;
        int mat = c >> 10, rem = c & 1023;
        int row = rem >> 6, d = rem & 63;
        const float* bias = (mat == 0) ? bq : (mat == 1) ? bk : bv;
        float v = qkvsel[(size_t)(mat * 32 + b * 16 + row) * 1024 + h * 64 + d]
                + bias[h * 64 + d];
        if (mat == 0) qs[row][d] = v;
        else if (mat == 1) ks[row][d] = v;
        else vs[row][d] = v;
    }
    __syncthreads();

    if (nx == 0 && t < 16) {
        float a = 0.f;
        #pragma unroll 8
        for (int d = 0; d < 64; ++d) a = fmaf(bq[h * 64 + d], ks[t][d], a);
        beta[b * 256 + h * 16 + t] = a;
    }

    const int nl = t & 127;
    const int n  = nx * 128 + nl;
    const int sg = t >> 7;

    // ---- C (Wq tile x ks) ----
    #pragma unroll
    for (int l = 0; l < 8; ++l) {
        int c = l * 256 + t;
        int rn = c >> 4, c4 = c & 15;
        float4 v = *(const float4*)(Wq + (size_t)(nx * 128 + rn) * 1024 + h * 64 + c4 * 4);
        wt[rn][c4 * 4 + 0] = v.x; wt[rn][c4 * 4 + 1] = v.y;
        wt[rn][c4 * 4 + 2] = v.z; wt[rn][c4 * 4 + 3] = v.w;
    }
    __syncthreads();
    {
        float acc[8] = {};
        #pragma unroll 8
        for (int d = 0; d < 64; ++d) {
            float wv = wt[nl][d];
            #pragma unroll
            for (int s = 0; s < 8; ++s)
                acc[s] = fmaf(wv, ks[sg * 8 + s][d], acc[s]);
        }
        #pragma unroll
        for (int s = 0; s < 8; ++s)
            ET[(size_t)(b * 512 + h * 16 + sg * 8 + s) * 1024 + n] = (__bf16)acc[s];
    }
    __syncthreads();

    // ---- D (Wk tile x qs) ----
    #pragma unroll
    for (int l = 0; l < 8; ++l) {
        int c = l * 256 + t;
        int rn = c >> 4, c4 = c & 15;
        float4 v = *(const float4*)(Wk + (size_t)(nx * 128 + rn) * 1024 + h * 64 + c4 * 4);
        wt[rn][c4 * 4 + 0] = v.x; wt[rn][c4 * 4 + 1] = v.y;
        wt[rn][c4 * 4 + 2] = v.z; wt[rn][c4 * 4 + 3] = v.w;
    }
    __syncthreads();
    {
        float acc[8] = {};
        #pragma unroll 8
        for (int d = 0; d < 64; ++d) {
            float wv = wt[nl][d];
            #pragma unroll
            for (int s = 0; s < 8; ++s)
                acc[s] = fmaf(wv, qs[sg * 8 + s][d], acc[s]);
        }
        #pragma unroll
        for (int s = 0; s < 8; ++s)
            ET[(size_t)(b * 512 + 256 + h * 16 + sg * 8 + s) * 1024 + n] = (__bf16)acc[s];
    }

    // ---- Vo^T (Wo direct x vs) ----
    {
        float acc[8] = {};
        #pragma unroll 8
        for (int d = 0; d < 64; ++d) {
            float wv = Wo[(size_t)(h * 64 + d) * 1024 + n];
            #pragma unroll
            for (int s = 0; s < 8; ++s)
                acc[s] = fmaf(wv, vs[sg * 8 + s][d], acc[s]);
        }
        #pragma unroll
        for (int s = 0; s < 8; ++s)
            VoT[((size_t)b * 1024 + n) * 256 + h * 16 + sg * 8 + s] = (__bf16)acc[s];
    }
}

// ---------------------------------------------------------------------------
// Score GEMM: S = X @ E (unchanged). Grid (4,32,2) = 256 blocks.
// ---------------------------------------------------------------------------
__global__ void __launch_bounds__(256) gemm_scores(
    const __bf16* __restrict__ xb, const __bf16* __restrict__ ET,
    float* __restrict__ Ssp, float* __restrict__ SdT)
{
    __shared__ __bf16 As[64 * 64];
    __shared__ __bf16 Bs[128 * 64];

    const int b    = blockIdx.z;
    const int bn   = blockIdx.x * 128;
    const int bm   = blockIdx.y * 64;
    const int t    = threadIdx.x;
    const int wave = t >> 6;
    const int lane = t & 63;
    const int wm   = (wave & 1) * 32;
    const int wn   = (wave >> 1) * 64;
    const int fr   = lane & 15;
    const int fq   = lane >> 4;
    const int K    = Dd;

    const __bf16* A  = xb + (size_t)b * Ss * Dd;
    const __bf16* BT = ET + (size_t)b * 512 * 1024 + (size_t)bn * 1024;

    f32x4 acc[2][4] = {};

    for (int k0 = 0; k0 < K; k0 += 64) {
        #pragma unroll
        for (int l = 0; l < 2; ++l) {
            int c = l * 256 + t;
            int row = c >> 3, seg = (c & 7) ^ (row & 7);
            gld_lds16(A + (size_t)(bm + row) * K + k0 + seg * 8,
                      As + (size_t)(l * 256 + wave * 64) * 8);
        }
        #pragma unroll
        for (int l = 0; l < 4; ++l) {
            int c = l * 256 + t;
            int row = c >> 3, seg = (c & 7) ^ (row & 7);
            gld_lds16(BT + (size_t)row * K + k0 + seg * 8,
                      Bs + (size_t)(l * 256 + wave * 64) * 8);
        }
        __syncthreads();
        #pragma unroll
        for (int s = 0; s < 2; ++s) {
            bf16x8 af[2], bf[4];
            #pragma unroll
            for (int i = 0; i < 2; ++i) {
                int row = wm + i * 16 + fr;
                af[i] = *(const bf16x8*)(As + row * 64 + (((s * 4 + fq) ^ (row & 7)) * 8));
            }
            #pragma unroll
            for (int j = 0; j < 4; ++j) {
                int row = wn + j * 16 + fr;
                bf[j] = *(const bf16x8*)(Bs + row * 64 + (((s * 4 + fq) ^ (row & 7)) * 8));
            }
            #pragma unroll
            for (int i = 0; i < 2; ++i)
                #pragma unroll
                for (int j = 0; j < 4; ++j)
                    acc[i][j] = __builtin_amdgcn_mfma_f32_16x16x32_bf16(af[i], bf[j], acc[i][j], 0, 0, 0);
        }
        __syncthreads();
    }

    const int cr = (lane >> 4) * 4;
    const int cc = lane & 15;
    #pragma unroll
    for (int j = 0; j < 4; ++j) {
        int col = bn + wn + j * 16 + cc;
        #pragma unroll
        for (int i = 0; i < 2; ++i) {
            int row0 = bm + wm + i * 16 + cr;
            if (col < 256) {
                #pragma unroll
                for (int r = 0; r < 4; ++r)
                    Ssp[((size_t)b * 2048 + row0 + r) * 256 + col] = acc[i][j][r];
            } else {
                *(f32x4*)(SdT + ((size_t)b * 256 + col - 256) * 2048 + row0) = acc[i][j];
            }
        }
    }
}

// ---------------------------------------------------------------------------
// FUSED softmaxes (fence-free union, verified): bx<512 sparse rows;
// bx>=512 dense columns. Grid (768, 2).
// ---------------------------------------------------------------------------
__global__ void __launch_bounds__(256) sm_all(
    const float* __restrict__ Ssp, const float* __restrict__ beta,
    __bf16* __restrict__ Wsp,
    const float* __restrict__ SdT, __bf16* __restrict__ WdT)
{
    __shared__ float red[256];
    const int b = blockIdx.y;
    const int t = threadIdx.x;

    if (blockIdx.x < 512) {
        const int r = blockIdx.x * 4 + (t >> 6);
        const int l = t & 63;
        float4 v  = *(const float4*)(Ssp + ((size_t)b * 2048 + r) * 256 + l * 4);
        float4 bt = *(const float4*)(beta + b * 256 + l * 4);
        float e0 = __expf((v.x + bt.x) * 0.125f);
        float e1 = __expf((v.y + bt.y) * 0.125f);
        float e2 = __expf((v.z + bt.z) * 0.125f);
        float e3 = __expf((v.w + bt.w) * 0.125f);
        float ps = e0 + e1 + e2 + e3;
        ps += __shfl_xor(ps, 1, 64);
        ps += __shfl_xor(ps, 2, 64);
        float inv = 1.f / ps;
        bf16x4 w = { (__bf16)(e0 * inv), (__bf16)(e1 * inv),
                     (__bf16)(e2 * inv), (__bf16)(e3 * inv) };
        *(bf16x4*)(Wsp + ((size_t)b * 2048 + r) * 256 + l * 4) = w;
    } else {
        const int cx = blockIdx.x - 512;
        const float* Sp = SdT + ((size_t)b * 256 + cx) * 2048;
        float4 v0 = *(const float4*)(Sp + t * 8);
        float4 v1 = *(const float4*)(Sp + t * 8 + 4);
        float e[8];
        e[0] = __expf(v0.x * 0.125f); e[1] = __expf(v0.y * 0.125f);
        e[2] = __expf(v0.z * 0.125f); e[3] = __expf(v0.w * 0.125f);
        e[4] = __expf(v1.x * 0.125f); e[5] = __expf(v1.y * 0.125f);
        e[6] = __expf(v1.z * 0.125f); e[7] = __expf(v1.w * 0.125f);
        float ps = 0.f;
        #pragma unroll
        for (int i = 0; i < 8; ++i) ps += e[i];
        red[t] = ps;
        __syncthreads();
        for (int off = 128; off > 0; off >>= 1) {
            if (t < off) red[t] += red[t + off];
            __syncthreads();
        }
        float inv = 1.f / red[0];
        bf16x8 w;
        #pragma unroll
        for (int i = 0; i < 8; ++i) w[i] = (__bf16)(e[i] * inv);
        *(bf16x8*)(WdT + ((size_t)b * 256 + cx) * 2048 + t * 8) = w;
    }
}

// ---------------------------------------------------------------------------
// Shared GEMM tile body (64x128, BK=64, 4 waves, XOR-swizzled LDS).
// ---------------------------------------------------------------------------
__device__ __forceinline__ void gemm_bt_body(
    __bf16* As, __bf16* Bs,
    const __bf16* __restrict__ A, const __bf16* __restrict__ BT,
    const float* __restrict__ bias, float* __restrict__ C,
    int N, int K, int bm, int bn, int kc, int kchunks, int t)
{
    const int wave = t >> 6;
    const int lane = t & 63;
    const int wm   = (wave & 1) * 32;
    const int wn   = (wave >> 1) * 64;
    const int fr   = lane & 15;
    const int fq   = lane >> 4;
    const int KC   = K / kchunks;
    const int kend = (kc + 1) * KC;

    f32x4 acc[2][4] = {};

    for (int k0 = kc * KC; k0 < kend; k0 += 64) {
        #pragma unroll
        for (int l = 0; l < 2; ++l) {
            int c = l * 256 + t;
            int row = c >> 3, seg = (c & 7) ^ (row & 7);
            gld_lds16(A + (size_t)(bm + row) * K + k0 + seg * 8,
                      As + (size_t)(l * 256 + wave * 64) * 8);
        }
        #pragma unroll
        for (int l = 0; l < 4; ++l) {
            int c = l * 256 + t;
            int row = c >> 3, seg = (c & 7) ^ (row & 7);
            gld_lds16(BT + (size_t)(bn + row) * K + k0 + seg * 8,
                      Bs + (size_t)(l * 256 + wave * 64) * 8);
        }
        __syncthreads();
        #pragma unroll
        for (int s = 0; s < 2; ++s) {
            bf16x8 af[2], bf[4];
            #pragma unroll
            for (int i = 0; i < 2; ++i) {
                int row = wm + i * 16 + fr;
                af[i] = *(const bf16x8*)(As + row * 64 + (((s * 4 + fq) ^ (row & 7)) * 8));
            }
            #pragma unroll
            for (int j = 0; j < 4; ++j) {
                int row = wn + j * 16 + fr;
                bf[j] = *(const bf16x8*)(Bs + row * 64 + (((s * 4 + fq) ^ (row & 7)) * 8));
            }
            #pragma unroll
            for (int i = 0; i < 2; ++i)
                #pragma unroll
                for (int j = 0; j < 4; ++j)
                    acc[i][j] = __builtin_amdgcn_mfma_f32_16x16x32_bf16(af[i], bf[j], acc[i][j], 0, 0, 0);
        }
        __syncthreads();
    }

    const int cr = (lane >> 4) * 4;
    const int cc = lane & 15;
    #pragma unroll
    for (int j = 0; j < 4; ++j) {
        int col = bn + wn + j * 16 + cc;
        if (kchunks == 1) {
            float bb = bias ? bias[col] : 0.f;
            #pragma unroll
            for (int i = 0; i < 2; ++i)
                #pragma unroll
                for (int r = 0; r < 4; ++r)
                    C[(size_t)(bm + wm + i * 16 + cr + r) * N + col] = acc[i][j][r] + bb;
        } else {
            #pragma unroll
            for (int i = 0; i < 2; ++i)
                #pragma unroll
                for (int r = 0; r < 4; ++r)
                    atomicAdd(C + (size_t)(bm + wm + i * 16 + cr + r) * N + col, acc[i][j][r]);
        }
    }
}

// ---------------------------------------------------------------------------
// FUSED output GEMMs (fence-free union, verified): id<512 -> out =
// W_sp @ Vo + bo; id>=512 -> Y = W_dn @ X (split-K x2, atomics).
// ---------------------------------------------------------------------------
__global__ void __launch_bounds__(256) gemm_bt2x(
    const __bf16* __restrict__ Wsp, const __bf16* __restrict__ VoT,
    const float* __restrict__ bo, float* __restrict__ out,
    const __bf16* __restrict__ WdT, const __bf16* __restrict__ xbT,
    float* __restrict__ Y)
{
    __shared__ __bf16 As[64 * 64];
    __shared__ __bf16 Bs[128 * 64];
    const int t = threadIdx.x;
    int id = blockIdx.x;
    if (id < 512) {
        int bx = id & 7, by = (id >> 3) & 31, bz = id >> 8;
        gemm_bt_body(As, Bs,
                     Wsp + (size_t)bz * 2048 * 256, VoT + (size_t)bz * 1024 * 256,
                     bo, out + (size_t)bz * 2048 * 1024,
                     1024, 256, by * 64, bx * 128, 0, 1, t);
    } else {
        id -= 512;
        int bx = id & 7, by = (id >> 3) & 3, z = id >> 5;   // z in 0..3
        int batch = z >> 1, kc = z & 1;
        gemm_bt_body(As, Bs,
                     WdT + (size_t)batch * 256 * 2048, xbT + (size_t)batch * 1024 * 2048,
                     nullptr, Y + (size_t)batch * 256 * 1024,
                     1024, 2048, by * 64, bx * 128, kc, 2, t);
    }
}

// ---------------------------------------------------------------------------
// Dense finalize A (split-K, 256 blocks): zbuf (init bv) += Y @ Wv chunk.
// Grid (16 h, 8 kc, 2 b). Unchanged.
// ---------------------------------------------------------------------------
__global__ void __launch_bounds__(256) dense_z2(
    const float* __restrict__ Y, const float* __restrict__ Wv,
    float* __restrict__ zbuf)
{
    const int h = blockIdx.x, kc = blockIdx.y, b = blockIdx.z;
    const int t = threadIdx.x;
    __shared__ float Ys[16][128];
    const int k0 = kc * 128;
    #pragma unroll
    for (int l = 0; l < 2; ++l) {
        int c = l * 256 + t;
        int row = c >> 5, c4 = c & 31;
        *(float4*)&Ys[row][c4 * 4] =
            *(const float4*)(Y + ((size_t)(b * 256 + h * 16 + row)) * 1024 + k0 + c4 * 4);
    }
    __syncthreads();
    const int d = t & 63, tg = t >> 6;
    float acc[4] = {};
    #pragma unroll 8
    for (int kk = 0; kk < 128; ++kk) {
        float wv = Wv[(size_t)(k0 + kk) * 1024 + h * 64 + d];
        #pragma unroll
        for (int tt = 0; tt < 4; ++tt)
            acc[tt] = fmaf(Ys[tg * 4 + tt][kk], wv, acc[tt]);
    }
    #pragma unroll
    for (int tt = 0; tt < 4; ++tt)
        atomicAdd(zbuf + ((size_t)(b * 16 + tg * 4 + tt)) * 1024 + h * 64 + d, acc[tt]);
}

// ---------------------------------------------------------------------------
// FUSED dense finalize B + scatter (R5-verified): obuf (init bo) += z @ Wo
// chunk; last-arriving block per batch scatters obuf to out[sel].
// Grid (16, 8, 2).
// ---------------------------------------------------------------------------
__global__ void __launch_bounds__(256) dense_fin(
    const float* __restrict__ zbuf, const float* __restrict__ Wo,
    float* __restrict__ obuf, int* __restrict__ cnt,
    const int* __restrict__ sel_idx, float* __restrict__ out)
{
    const int nt = blockIdx.x, kc = blockIdx.y, b = blockIdx.z;
    const int t = threadIdx.x;
    __shared__ float zs[16][128];
    __shared__ int lastf;
    __shared__ int sj[16];
    const int k0 = kc * 128;
    #pragma unroll
    for (int l = 0; l < 2; ++l) {
        int c = l * 256 + t;
        int row = c >> 5, c4 = c & 31;
        *(float4*)&zs[row][c4 * 4] =
            *(const float4*)(zbuf + ((size_t)(b * 16 + row)) * 1024 + k0 + c4 * 4);
    }
    __syncthreads();
    const int n = nt * 64 + (t & 63), tg = t >> 6;
    float acc[4] = {};
    #pragma unroll 8
    for (int kk = 0; kk < 128; ++kk) {
        float wv = Wo[(size_t)(k0 + kk) * 1024 + n];
        #pragma unroll
        for (int tt = 0; tt < 4; ++tt)
            acc[tt] = fmaf(zs[tg * 4 + tt][kk], wv, acc[tt]);
    }
    #pragma unroll
    for (int tt = 0; tt < 4; ++tt)
        atomicAdd(obuf + ((size_t)(b * 16 + tg * 4 + tt)) * 1024 + n, acc[tt]);

    __threadfence();
    if (t == 0) lastf = (atomicAdd(&cnt[4 + b], 1) == 127);
    __syncthreads();
    if (!lastf) return;
    __threadfence();
    if (t < 16) sj[t] = sel_idx[b * 16 + t];
    __syncthreads();
    #pragma unroll
    for (int r = 0; r < 16; ++r) {
        float4 v = *(const float4*)(obuf + ((size_t)(b * 16 + r)) * 1024 + t * 4);
        *(float4*)(out + ((size_t)(b * 2048 + sj[r])) * 1024 + t * 4) = v;
    }
}

// ---------------------------------------------------------------------------
extern "C" void kernel_launch(void* const* d_in, const int* in_sizes, int n_in,
                              void* d_out, int out_size, void* d_ws, size_t ws_size,
                              hipStream_t stream)
{
    const float* x   = (const float*)d_in[0];
    const float* Wq  = (const float*)d_in[1];
    const float* bq  = (const float*)d_in[2];
    const float* Wk  = (const float*)d_in[3];
    const float* bk  = (const float*)d_in[4];
    const float* Wv  = (const float*)d_in[5];
    const float* bv  = (const float*)d_in[6];
    const float* Wo  = (const float*)d_in[7];
    const float* bo  = (const float*)d_in[8];
    const float* Ws1 = (const float*)d_in[9];
    const float* bs1 = (const float*)d_in[10];
    const float* Ws2 = (const float*)d_in[11];
    float* out = (float*)d_out;

    const size_t MSD = (size_t)Bb * Ss * Dd;   // 4,194,304

    char* p = (char*)d_ws;
    __bf16* xb    = (__bf16*)p; p += MSD * sizeof(__bf16);
    __bf16* xbT   = (__bf16*)p; p += MSD * sizeof(__bf16);
    __bf16* W1Th  = (__bf16*)p; p += (size_t)512 * 1024 * sizeof(__bf16);
    __bf16* ET    = (__bf16*)p; p += (size_t)2 * 512 * 1024 * sizeof(__bf16);
    __bf16* VoT   = (__bf16*)p; p += (size_t)2 * 1024 * 256 * sizeof(__bf16);
    __bf16* Wsp   = (__bf16*)p; p += (size_t)2 * 2048 * 256 * sizeof(__bf16);
    __bf16* WdT   = (__bf16*)p; p += (size_t)2 * 256 * 2048 * sizeof(__bf16);
    float* Ssp    = (float*)p; p += (size_t)2 * 2048 * 256 * sizeof(float);
    float* SdT    = (float*)p; p += (size_t)2 * 256 * 2048 * sizeof(float);
    float* Y      = (float*)p; p += (size_t)2 * 256 * 1024 * sizeof(float);
    float* zbuf   = (float*)p; p += (size_t)2 * 16 * 1024 * sizeof(float);
    float* obuf   = (float*)p; p += (size_t)2 * 16 * 1024 * sizeof(float);
    float* imp    = (float*)p; p += (size_t)Bb * Ss * sizeof(float);
    float* hbuf   = (float*)p; p += (size_t)Bb * 64 * 512 * sizeof(float);
    float* qkvsel = (float*)p; p += (size_t)3 * 32 * 1024 * sizeof(float);
    float* beta   = (float*)p; p += (size_t)2 * 256 * sizeof(float);
    int* cnt      = (int*)p; p += 8 * sizeof(int);
    int* sel_idx  = (int*)p; p += (size_t)Bb * Kk * sizeof(int);
    int* cand_idx = (int*)p; p += (size_t)Bb * 64 * sizeof(int);
    int* ccount   = (int*)p; p += Bb * sizeof(int);

    // 1) prep: inits (1024) + transpose&pack x once (4096) + Ws1 T (512).
    prep_kernel<<<dim3(5632), 256, 0, stream>>>(
        x, xb, xbT, imp, hbuf, qkvsel, ccount, Ws1, W1Th,
        bv, bo, Y, zbuf, obuf, cnt);
    // 2) FUSED: indexer GEMM + fast single-wave topk (last block per b).
    gemm_ind_topk<<<dim3(4, 64), 256, 0, stream>>>(
        xb, W1Th, bs1, Ws2, imp, cnt, cand_idx, ccount);
    // 3) exact rescore: parallel partial-h, then fused finalize+selection.
    rescore_h<<<dim3(64, 16, Bb), 256, 0, stream>>>(x, Ws1, cand_idx, ccount, hbuf);
    rescore_fin_sel<<<dim3(Bb), 256, 0, stream>>>(
        hbuf, bs1, Ws2, cand_idx, ccount, sel_idx);
    // 4) exact f32 projections of the 32 selected rows.
    proj_sel<<<dim3(8, 3, 8), 256, 0, stream>>>(x, Wq, Wk, Wv, sel_idx, qkvsel);
    // 5) build algebraic operands C, D (-> ET), Vo^T, beta.
    build_cdvo<<<dim3(8, 16, 2), 256, 0, stream>>>(
        Wq, Wk, Wo, bq, bk, bv, qkvsel, beta, ET, VoT);
    // 6) all scores in one GEMM: S = X @ [C|D] (256 blocks).
    gemm_scores<<<dim3(4, 32, 2), 256, 0, stream>>>(xb, ET, Ssp, SdT);
    // 7) FUSED softmaxes -> bf16 weight matrices.
    sm_all<<<dim3(768, 2), 256, 0, stream>>>(Ssp, beta, Wsp, SdT, WdT);
    // 8) FUSED output GEMMs: sparse out (512 blocks) + Y = W_dn @ X (128).
    gemm_bt2x<<<dim3(640), 256, 0, stream>>>(Wsp, VoT, bo, out, WdT, xbT, Y);
    // 9) dense tail: zbuf(+=bv) = Y@Wv; obuf(+=bo) = z@Wo + scatter (fused).
    dense_z2<<<dim3(16, 8, 2), 256, 0, stream>>>(Y, Wv, zbuf);
    dense_fin<<<dim3(16, 8, 2), 256, 0, stream>>>(zbuf, Wo, obuf, cnt, sel_idx, out);
}

// Round 8
// 256.792 us; speedup vs baseline: 1.1277x; 1.1277x over previous
//
#include <hip/hip_runtime.h>
#include <math.h>

// Problem constants
constexpr int Bb = 2, Ss = 2048, Dd = 1024, Hh = 16, Kk = 16;
constexpr float DELTA = 0.02f;   // candidate margin (~30 sigma of bf16 approx error)

typedef __bf16 bf16x8 __attribute__((ext_vector_type(8)));
typedef __bf16 bf16x4 __attribute__((ext_vector_type(4)));
typedef float  f32x4  __attribute__((ext_vector_type(4)));

__device__ __forceinline__ void gld_lds16(const void* g, void* l) {
    __builtin_amdgcn_global_load_lds(
        (const __attribute__((address_space(1))) unsigned int*)g,
        (__attribute__((address_space(3))) unsigned int*)l, 16, 0, 0);
}

// ---------------------------------------------------------------------------
// Merged prep: bid<1024 -> float4 inits (Y=0, hbuf=0, qkvsel=0, imp=0,
// zbuf=bv, obuf=bo); 1024..5119 -> per-batch transpose x -> xbT AND pack
// x -> xb from the same tile (x read ONCE); bid>=5120 -> Ws1 T -> W1Th.
// ---------------------------------------------------------------------------
__global__ void __launch_bounds__(256) prep_kernel(
    const float* __restrict__ x, __bf16* __restrict__ xb,
    __bf16* __restrict__ xbT,
    float* __restrict__ imp, float* __restrict__ hbuf,
    float* __restrict__ qkvsel, int* __restrict__ ccount,
    const float* __restrict__ Ws1, __bf16* __restrict__ W1Th,
    const float* __restrict__ bv, const float* __restrict__ bo,
    float* __restrict__ Y, float* __restrict__ zbuf,
    float* __restrict__ obuf)
{
    __shared__ float tile[32][33];
    const int bid = blockIdx.x;
    const int t   = threadIdx.x;

    if (bid < 1024) {
        int i = bid * 256 + t;                       // float4 index
        float4 z4 = {0.f, 0.f, 0.f, 0.f};
        if (i < 131072) ((float4*)Y)[i] = z4;
        if (i < 16384)  ((float4*)hbuf)[i] = z4;
        if (i < 24576)  ((float4*)qkvsel)[i] = z4;
        if (i < 8192)   ((float4*)zbuf)[i] = ((const float4*)bv)[i & 255];
        if (i < 8192)   ((float4*)obuf)[i] = ((const float4*)bo)[i & 255];
        if (i < 1024)   ((float4*)imp)[i] = z4;
        if (i < Bb)     ccount[i] = 0;
        return;
    }
    if (bid < 5120) {
        // transpose + pack: xbT[b][c][r] = x[b][r][c]; xb = bf16(x)
        int tid = bid - 1024;          // 0..4095, 2048 tiles per b
        int b   = tid >> 11;
        int rem = tid & 2047;
        int rt  = rem >> 5;            // 64 row-tiles (2048/32)
        int ct  = rem & 31;            // 32 col-tiles (1024/32)
        int tx = t & 31, ty = t >> 5;
        const float* xp = x + (size_t)b * Ss * Dd;
        __bf16* xbp = xb + (size_t)b * Ss * Dd;
        #pragma unroll
        for (int i2 = 0; i2 < 32; i2 += 8) {
            float v = xp[(size_t)(rt * 32 + ty + i2) * 1024 + ct * 32 + tx];
            tile[ty + i2][tx] = v;
            xbp[(size_t)(rt * 32 + ty + i2) * 1024 + ct * 32 + tx] = (__bf16)v;
        }
        __syncthreads();
        __bf16* xT = xbT + (size_t)b * Dd * Ss;
        #pragma unroll
        for (int i2 = 0; i2 < 32; i2 += 8)
            xT[(size_t)(ct * 32 + ty + i2) * 2048 + rt * 32 + tx] = (__bf16)tile[tx][ty + i2];
        return;
    }
    {
        int tid = bid - 5120;          // 0..511
        int n0 = (tid & 15) * 32;
        int k0 = (tid >> 4) * 32;
        int tx = t & 31, ty = t >> 5;
        #pragma unroll
        for (int i2 = 0; i2 < 32; i2 += 8)
            tile[ty + i2][tx] = Ws1[(size_t)(k0 + ty + i2) * 512 + n0 + tx];
        __syncthreads();
        #pragma unroll
        for (int i2 = 0; i2 < 32; i2 += 8)
            W1Th[(size_t)(n0 + ty + i2) * 1024 + k0 + tx] = (__bf16)tile[tx][ty + i2];
    }
}

// ---------------------------------------------------------------------------
// Indexer GEMM: imp = rowsum(relu(x@Ws1+bs1)*Ws2). 64x128 tile, BK=64,
// 4 waves, XOR-swizzled LDS. Grid (4 cb, 64 mtiles) = 256 blocks. NO fence.
// ---------------------------------------------------------------------------
__global__ void __launch_bounds__(256) gemm_ind(
    const __bf16* __restrict__ xb, const __bf16* __restrict__ W1Th,
    const float* __restrict__ bs1, const float* __restrict__ Ws2,
    float* __restrict__ imp)
{
    __shared__ __bf16 As[64 * 64];
    __shared__ __bf16 Bs[128 * 64];

    const int cb   = blockIdx.x;
    const int bm   = blockIdx.y * 64;
    const int t    = threadIdx.x;
    const int wave = t >> 6;
    const int lane = t & 63;
    const int wm   = (wave & 1) * 32;
    const int wn   = (wave >> 1) * 64;
    const int fr   = lane & 15;
    const int fq   = lane >> 4;
    const int K    = Dd;

    const __bf16* BT = W1Th + (size_t)cb * 128 * 1024;

    f32x4 acc[2][4] = {};

    for (int k0 = 0; k0 < K; k0 += 64) {
        #pragma unroll
        for (int l = 0; l < 2; ++l) {
            int c = l * 256 + t;
            int row = c >> 3, seg = (c & 7) ^ (row & 7);
            gld_lds16(xb + (size_t)(bm + row) * K + k0 + seg * 8,
                      As + (size_t)(l * 256 + wave * 64) * 8);
        }
        #pragma unroll
        for (int l = 0; l < 4; ++l) {
            int c = l * 256 + t;
            int row = c >> 3, seg = (c & 7) ^ (row & 7);
            gld_lds16(BT + (size_t)row * K + k0 + seg * 8,
                      Bs + (size_t)(l * 256 + wave * 64) * 8);
        }
        __syncthreads();
        #pragma unroll
        for (int s = 0; s < 2; ++s) {
            bf16x8 af[2], bf[4];
            #pragma unroll
            for (int i = 0; i < 2; ++i) {
                int row = wm + i * 16 + fr;
                af[i] = *(const bf16x8*)(As + row * 64 + (((s * 4 + fq) ^ (row & 7)) * 8));
            }
            #pragma unroll
            for (int j = 0; j < 4; ++j) {
                int row = wn + j * 16 + fr;
                bf[j] = *(const bf16x8*)(Bs + row * 64 + (((s * 4 + fq) ^ (row & 7)) * 8));
            }
            #pragma unroll
            for (int i = 0; i < 2; ++i)
                #pragma unroll
                for (int j = 0; j < 4; ++j)
                    acc[i][j] = __builtin_amdgcn_mfma_f32_16x16x32_bf16(af[i], bf[j], acc[i][j], 0, 0, 0);
        }
        __syncthreads();
    }

    const int cr = (lane >> 4) * 4;
    const int cc = lane & 15;
    float bb[4], w2[4];
    #pragma unroll
    for (int j = 0; j < 4; ++j) {
        int col = cb * 128 + wn + j * 16 + cc;
        bb[j] = bs1[col];
        w2[j] = Ws2[col];
    }
    #pragma unroll
    for (int i = 0; i < 2; ++i) {
        #pragma unroll
        for (int r = 0; r < 4; ++r) {
            float vsum = 0.f;
            #pragma unroll
            for (int j = 0; j < 4; ++j)
                vsum += fmaxf(acc[i][j][r] + bb[j], 0.f) * w2[j];
            #pragma unroll
            for (int off = 8; off > 0; off >>= 1)
                vsum += __shfl_xor(vsum, off, 16);
            if (cc == 0)
                atomicAdd(imp + (bm + wm + i * 16 + cr + r), vsum);
        }
    }
}

// ---------------------------------------------------------------------------
// FAST candidate generation (standalone; logic verified R7): wave-0 argmax
// over LDS with no syncthreads in the 16-iter loop; then threshold band
// with all 256 threads. Grid (Bb), 256 threads.
// ---------------------------------------------------------------------------
__global__ void __launch_bounds__(256) topk_fast(
    const float* __restrict__ imp, int* __restrict__ cand_idx,
    int* __restrict__ ccount)
{
    __shared__ float vals[2048];
    __shared__ float thr_s;
    __shared__ int   cnt_s;
    const int b = blockIdx.x;
    const int t = threadIdx.x;

    #pragma unroll
    for (int e = 0; e < 8; ++e)
        vals[t + 256 * e] = imp[b * Ss + t + 256 * e];
    __syncthreads();

    if (t < 64) {
        const int base = t * 32;
        for (int it = 0; it < Kk; ++it) {
            float best = -1e30f; int bidx = 0x7fffffff;
            #pragma unroll 8
            for (int j = 0; j < 32; ++j) {
                float v = vals[base + j];
                if (v > best) { best = v; bidx = base + j; }
            }
            #pragma unroll
            for (int off = 32; off > 0; off >>= 1) {
                float ov = __shfl_xor(best, off, 64);
                int   oi = __shfl_xor(bidx, off, 64);
                if (ov > best || (ov == best && oi < bidx)) { best = ov; bidx = oi; }
            }
            if (t == 0) {
                cand_idx[b * 64 + it] = bidx;
                vals[bidx] = -1e30f;
                if (it == Kk - 1) { thr_s = best - DELTA; cnt_s = Kk; }
            }
        }
    }
    __syncthreads();

    float thr = thr_s;
    #pragma unroll
    for (int e = 0; e < 8; ++e) {
        if (vals[t + 256 * e] > thr) {
            int p = atomicAdd(&cnt_s, 1);
            if (p < 64) cand_idx[b * 64 + p] = t + 256 * e;
        }
    }
    __syncthreads();
    if (t == 0) ccount[b] = min(cnt_s, 64);
}

// ---------------------------------------------------------------------------
// Exact f32 rescore, phase 1 (unchanged, proven). NO trailing fence.
// ---------------------------------------------------------------------------
__global__ void __launch_bounds__(256) rescore_h(
    const float* __restrict__ x, const float* __restrict__ Ws1,
    const int* __restrict__ cand_idx, const int* __restrict__ ccount,
    float* __restrict__ hbuf)
{
    const int c = blockIdx.x, kc = blockIdx.y, b = blockIdx.z;
    if (c >= ccount[b]) return;
    const int row = cand_idx[b * 64 + c];
    const int t = threadIdx.x;
    const int k0 = kc * 64;

    __shared__ float xs[64];
    if (t < 16)
        ((float4*)xs)[t] = ((const float4*)(x + ((size_t)(b * Ss + row)) * Dd + k0))[t];
    __syncthreads();

    float a0 = 0.f, a1 = 0.f;
    const float* W = Ws1 + (size_t)k0 * 512;
    #pragma unroll 16
    for (int kk = 0; kk < 64; ++kk) {
        float xv = xs[kk];
        a0 = fmaf(xv, W[kk * 512 + t], a0);
        a1 = fmaf(xv, W[kk * 512 + t + 256], a1);
    }
    float* hb = hbuf + ((size_t)(b * 64 + c)) * 512;
    atomicAdd(hb + t, a0);
    atomicAdd(hb + t + 256, a1);
}

// ---------------------------------------------------------------------------
// MERGED rescore phase-2 + final selection (unchanged, proven R6).
// ---------------------------------------------------------------------------
__global__ void __launch_bounds__(256) rescore_fin_sel(
    const float* __restrict__ hbuf, const float* __restrict__ bs1,
    const float* __restrict__ Ws2, const int* __restrict__ cand_idx,
    const int* __restrict__ ccount, int* __restrict__ sel_idx)
{
    const int b = blockIdx.x;
    const int t = threadIdx.x;
    __shared__ float czv[64];
    __shared__ int   cidx[64];
    const int cntb = ccount[b];

    {
        const int cc = t >> 2, part = t & 3;
        const float* hb = hbuf + ((size_t)(b * 64 + cc)) * 512;
        float z = 0.f;
        const int j0 = part * 128;
        for (int j = j0; j < j0 + 128; ++j)
            z += fmaxf(hb[j] + bs1[j], 0.f) * Ws2[j];
        z += __shfl_xor(z, 1, 4);
        z += __shfl_xor(z, 2, 4);
        if (part == 0) { czv[cc] = z; cidx[cc] = cand_idx[b * 64 + cc]; }
    }
    __syncthreads();

    if (t < 64) {
        float val = (t < cntb) ? czv[t] : -1e30f;
        int   row = (t < cntb) ? cidx[t] : 0x7fffffff;
        for (int it = 0; it < Kk; ++it) {
            float bv = val; int br = row;
            #pragma unroll
            for (int off = 1; off < 64; off <<= 1) {
                float ov = __shfl_xor(bv, off, 64);
                int   orw = __shfl_xor(br, off, 64);
                if (ov > bv || (ov == bv && orw < br)) { bv = ov; br = orw; }
            }
            if (row == br) val = -1e30f;
            if (t == 0) sel_idx[b * Kk + it] = br;
        }
    }
}

// ---------------------------------------------------------------------------
// Exact f32 projections of the 32 selected rows (unchanged, proven).
// Grid (8 coltiles, 3 mats, 8 kchunks).
// ---------------------------------------------------------------------------
__global__ void __launch_bounds__(256) proj_sel(
    const float* __restrict__ x,
    const float* __restrict__ Wq, const float* __restrict__ Wk,
    const float* __restrict__ Wv,
    const int* __restrict__ sel_idx, float* __restrict__ qkvsel)
{
    const int cx = blockIdx.x;
    const int m  = blockIdx.y;
    const int kc = blockIdx.z;
    const int t  = threadIdx.x;
    __shared__ int   sj[32];
    __shared__ float xs[32][128];

    if (t < 32) sj[t] = sel_idx[t];
    __syncthreads();

    const int k0 = kc * 128;
    #pragma unroll
    for (int l = 0; l < 4; ++l) {
        int c = l * 256 + t;
        int r = c >> 5, kq = c & 31;
        int b = r >> 4;
        float4 v = *(const float4*)(x + ((size_t)(b * Ss + sj[r])) * Dd + k0 + kq * 4);
        *(float4*)&xs[r][kq * 4] = v;
    }
    __syncthreads();

    const float* W = (m == 0) ? Wq : (m == 1) ? Wk : Wv;
    const int col = cx * 128 + (t & 127);
    const int rh  = t >> 7;
    float acc[16] = {};
    #pragma unroll 4
    for (int kk = 0; kk < 128; ++kk) {
        float wv = W[(size_t)(k0 + kk) * 1024 + col];
        #pragma unroll
        for (int r = 0; r < 16; ++r)
            acc[r] = fmaf(xs[rh * 16 + r][kk], wv, acc[r]);
    }
    #pragma unroll
    for (int r = 0; r < 16; ++r)
        atomicAdd(qkvsel + (size_t)(m * 32 + rh * 16 + r) * 1024 + col, acc[r]);
}

// ---------------------------------------------------------------------------
// Build the algebraic operands (unchanged, proven). Grid (8,16,2).
// ---------------------------------------------------------------------------
__global__ void __launch_bounds__(256) build_cdvo(
    const float* __restrict__ Wq, const float* __restrict__ Wk,
    const float* __restrict__ Wo,
    const float* __restrict__ bq, const float* __restrict__ bk,
    const float* __restrict__ bv,
    const float* __restrict__ qkvsel, float* __restrict__ beta,
    __bf16* __restrict__ ET, __bf16* __restrict__ VoT)
{
    const int nx = blockIdx.x;
    const int h  = blockIdx.y;
    const int b  = blockIdx.z;
    const int t  = threadIdx.x;
    __shared__ float qs[16][64], ks[16][64], vs[16][64];
    __shared__ float wt[128][65];

    #pragma unroll
    for (int l = 0; l < 12; ++l) {
        int c = l * 256 + t;
        int mat = c >> 10, rem = c & 1023;
        int row = rem >> 6, d = rem & 63;
        const float* bias = (mat == 0) ? bq : (mat == 1) ? bk : bv;
        float v = qkvsel[(size_t)(mat * 32 + b * 16 + row) * 1024 + h * 64 + d]
                + bias[h * 64 + d];
        if (mat == 0) qs[row][d] = v;
        else if (mat == 1) ks[row][d] = v;
        else vs[row][d] = v;
    }
    __syncthreads();

    if (nx == 0 && t < 16) {
        float a = 0.f;
        #pragma unroll 8
        for (int d = 0; d < 64; ++d) a = fmaf(bq[h * 64 + d], ks[t][d], a);
        beta[b * 256 + h * 16 + t] = a;
    }

    const int nl = t & 127;
    const int n  = nx * 128 + nl;
    const int sg = t >> 7;

    // ---- C (Wq tile x ks) ----
    #pragma unroll
    for (int l = 0; l < 8; ++l) {
        int c = l * 256 + t;
        int rn = c >> 4, c4 = c & 15;
        float4 v = *(const float4*)(Wq + (size_t)(nx * 128 + rn) * 1024 + h * 64 + c4 * 4);
        wt[rn][c4 * 4 + 0] = v.x; wt[rn][c4 * 4 + 1] = v.y;
        wt[rn][c4 * 4 + 2] = v.z; wt[rn][c4 * 4 + 3] = v.w;
    }
    __syncthreads();
    {
        float acc[8] = {};
        #pragma unroll 8
        for (int d = 0; d < 64; ++d) {
            float wv = wt[nl][d];
            #pragma unroll
            for (int s = 0; s < 8; ++s)
                acc[s] = fmaf(wv, ks[sg * 8 + s][d], acc[s]);
        }
        #pragma unroll
        for (int s = 0; s < 8; ++s)
            ET[(size_t)(b * 512 + h * 16 + sg * 8 + s) * 1024 + n] = (__bf16)acc[s];
    }
    __syncthreads();

    // ---- D (Wk tile x qs) ----
    #pragma unroll
    for (int l = 0; l < 8; ++l) {
        int c = l * 256 + t;
        int rn = c >> 4, c4 = c & 15;
        float4 v = *(const float4*)(Wk + (size_t)(nx * 128 + rn) * 1024 + h * 64 + c4 * 4);
        wt[rn][c4 * 4 + 0] = v.x; wt[rn][c4 * 4 + 1] = v.y;
        wt[rn][c4 * 4 + 2] = v.z; wt[rn][c4 * 4 + 3] = v.w;
    }
    __syncthreads();
    {
        float acc[8] = {};
        #pragma unroll 8
        for (int d = 0; d < 64; ++d) {
            float wv = wt[nl][d];
            #pragma unroll
            for (int s = 0; s < 8; ++s)
                acc[s] = fmaf(wv, qs[sg * 8 + s][d], acc[s]);
        }
        #pragma unroll
        for (int s = 0; s < 8; ++s)
            ET[(size_t)(b * 512 + 256 + h * 16 + sg * 8 + s) * 1024 + n] = (__bf16)acc[s];
    }

    // ---- Vo^T (Wo direct x vs) ----
    {
        float acc[8] = {};
        #pragma unroll 8
        for (int d = 0; d < 64; ++d) {
            float wv = Wo[(size_t)(h * 64 + d) * 1024 + n];
            #pragma unroll
            for (int s = 0; s < 8; ++s)
                acc[s] = fmaf(wv, vs[sg * 8 + s][d], acc[s]);
        }
        #pragma unroll
        for (int s = 0; s < 8; ++s)
            VoT[((size_t)b * 1024 + n) * 256 + h * 16 + sg * 8 + s] = (__bf16)acc[s];
    }
}

// ---------------------------------------------------------------------------
// Score GEMM: S = X @ E (unchanged). Grid (4,32,2) = 256 blocks.
// ---------------------------------------------------------------------------
__global__ void __launch_bounds__(256) gemm_scores(
    const __bf16* __restrict__ xb, const __bf16* __restrict__ ET,
    float* __restrict__ Ssp, float* __restrict__ SdT)
{
    __shared__ __bf16 As[64 * 64];
    __shared__ __bf16 Bs[128 * 64];

    const int b    = blockIdx.z;
    const int bn   = blockIdx.x * 128;
    const int bm   = blockIdx.y * 64;
    const int t    = threadIdx.x;
    const int wave = t >> 6;
    const int lane = t & 63;
    const int wm   = (wave & 1) * 32;
    const int wn   = (wave >> 1) * 64;
    const int fr   = lane & 15;
    const int fq   = lane >> 4;
    const int K    = Dd;

    const __bf16* A  = xb + (size_t)b * Ss * Dd;
    const __bf16* BT = ET + (size_t)b * 512 * 1024 + (size_t)bn * 1024;

    f32x4 acc[2][4] = {};

    for (int k0 = 0; k0 < K; k0 += 64) {
        #pragma unroll
        for (int l = 0; l < 2; ++l) {
            int c = l * 256 + t;
            int row = c >> 3, seg = (c & 7) ^ (row & 7);
            gld_lds16(A + (size_t)(bm + row) * K + k0 + seg * 8,
                      As + (size_t)(l * 256 + wave * 64) * 8);
        }
        #pragma unroll
        for (int l = 0; l < 4; ++l) {
            int c = l * 256 + t;
            int row = c >> 3, seg = (c & 7) ^ (row & 7);
            gld_lds16(BT + (size_t)row * K + k0 + seg * 8,
                      Bs + (size_t)(l * 256 + wave * 64) * 8);
        }
        __syncthreads();
        #pragma unroll
        for (int s = 0; s < 2; ++s) {
            bf16x8 af[2], bf[4];
            #pragma unroll
            for (int i = 0; i < 2; ++i) {
                int row = wm + i * 16 + fr;
                af[i] = *(const bf16x8*)(As + row * 64 + (((s * 4 + fq) ^ (row & 7)) * 8));
            }
            #pragma unroll
            for (int j = 0; j < 4; ++j) {
                int row = wn + j * 16 + fr;
                bf[j] = *(const bf16x8*)(Bs + row * 64 + (((s * 4 + fq) ^ (row & 7)) * 8));
            }
            #pragma unroll
            for (int i = 0; i < 2; ++i)
                #pragma unroll
                for (int j = 0; j < 4; ++j)
                    acc[i][j] = __builtin_amdgcn_mfma_f32_16x16x32_bf16(af[i], bf[j], acc[i][j], 0, 0, 0);
        }
        __syncthreads();
    }

    const int cr = (lane >> 4) * 4;
    const int cc = lane & 15;
    #pragma unroll
    for (int j = 0; j < 4; ++j) {
        int col = bn + wn + j * 16 + cc;
        #pragma unroll
        for (int i = 0; i < 2; ++i) {
            int row0 = bm + wm + i * 16 + cr;
            if (col < 256) {
                #pragma unroll
                for (int r = 0; r < 4; ++r)
                    Ssp[((size_t)b * 2048 + row0 + r) * 256 + col] = acc[i][j][r];
            } else {
                *(f32x4*)(SdT + ((size_t)b * 256 + col - 256) * 2048 + row0) = acc[i][j];
            }
        }
    }
}

// ---------------------------------------------------------------------------
// FUSED softmaxes (fence-free union, verified): bx<512 sparse rows;
// bx>=512 dense columns. Grid (768, 2).
// ---------------------------------------------------------------------------
__global__ void __launch_bounds__(256) sm_all(
    const float* __restrict__ Ssp, const float* __restrict__ beta,
    __bf16* __restrict__ Wsp,
    const float* __restrict__ SdT, __bf16* __restrict__ WdT)
{
    __shared__ float red[256];
    const int b = blockIdx.y;
    const int t = threadIdx.x;

    if (blockIdx.x < 512) {
        const int r = blockIdx.x * 4 + (t >> 6);
        const int l = t & 63;
        float4 v  = *(const float4*)(Ssp + ((size_t)b * 2048 + r) * 256 + l * 4);
        float4 bt = *(const float4*)(beta + b * 256 + l * 4);
        float e0 = __expf((v.x + bt.x) * 0.125f);
        float e1 = __expf((v.y + bt.y) * 0.125f);
        float e2 = __expf((v.z + bt.z) * 0.125f);
        float e3 = __expf((v.w + bt.w) * 0.125f);
        float ps = e0 + e1 + e2 + e3;
        ps += __shfl_xor(ps, 1, 64);
        ps += __shfl_xor(ps, 2, 64);
        float inv = 1.f / ps;
        bf16x4 w = { (__bf16)(e0 * inv), (__bf16)(e1 * inv),
                     (__bf16)(e2 * inv), (__bf16)(e3 * inv) };
        *(bf16x4*)(Wsp + ((size_t)b * 2048 + r) * 256 + l * 4) = w;
    } else {
        const int cx = blockIdx.x - 512;
        const float* Sp = SdT + ((size_t)b * 256 + cx) * 2048;
        float4 v0 = *(const float4*)(Sp + t * 8);
        float4 v1 = *(const float4*)(Sp + t * 8 + 4);
        float e[8];
        e[0] = __expf(v0.x * 0.125f); e[1] = __expf(v0.y * 0.125f);
        e[2] = __expf(v0.z * 0.125f); e[3] = __expf(v0.w * 0.125f);
        e[4] = __expf(v1.x * 0.125f); e[5] = __expf(v1.y * 0.125f);
        e[6] = __expf(v1.z * 0.125f); e[7] = __expf(v1.w * 0.125f);
        float ps = 0.f;
        #pragma unroll
        for (int i = 0; i < 8; ++i) ps += e[i];
        red[t] = ps;
        __syncthreads();
        for (int off = 128; off > 0; off >>= 1) {
            if (t < off) red[t] += red[t + off];
            __syncthreads();
        }
        float inv = 1.f / red[0];
        bf16x8 w;
        #pragma unroll
        for (int i = 0; i < 8; ++i) w[i] = (__bf16)(e[i] * inv);
        *(bf16x8*)(WdT + ((size_t)b * 256 + cx) * 2048 + t * 8) = w;
    }
}

// ---------------------------------------------------------------------------
// Shared GEMM tile body (64x128, BK=64, 4 waves, XOR-swizzled LDS).
// ---------------------------------------------------------------------------
__device__ __forceinline__ void gemm_bt_body(
    __bf16* As, __bf16* Bs,
    const __bf16* __restrict__ A, const __bf16* __restrict__ BT,
    const float* __restrict__ bias, float* __restrict__ C,
    int N, int K, int bm, int bn, int kc, int kchunks, int t)
{
    const int wave = t >> 6;
    const int lane = t & 63;
    const int wm   = (wave & 1) * 32;
    const int wn   = (wave >> 1) * 64;
    const int fr   = lane & 15;
    const int fq   = lane >> 4;
    const int KC   = K / kchunks;
    const int kend = (kc + 1) * KC;

    f32x4 acc[2][4] = {};

    for (int k0 = kc * KC; k0 < kend; k0 += 64) {
        #pragma unroll
        for (int l = 0; l < 2; ++l) {
            int c = l * 256 + t;
            int row = c >> 3, seg = (c & 7) ^ (row & 7);
            gld_lds16(A + (size_t)(bm + row) * K + k0 + seg * 8,
                      As + (size_t)(l * 256 + wave * 64) * 8);
        }
        #pragma unroll
        for (int l = 0; l < 4; ++l) {
            int c = l * 256 + t;
            int row = c >> 3, seg = (c & 7) ^ (row & 7);
            gld_lds16(BT + (size_t)(bn + row) * K + k0 + seg * 8,
                      Bs + (size_t)(l * 256 + wave * 64) * 8);
        }
        __syncthreads();
        #pragma unroll
        for (int s = 0; s < 2; ++s) {
            bf16x8 af[2], bf[4];
            #pragma unroll
            for (int i = 0; i < 2; ++i) {
                int row = wm + i * 16 + fr;
                af[i] = *(const bf16x8*)(As + row * 64 + (((s * 4 + fq) ^ (row & 7)) * 8));
            }
            #pragma unroll
            for (int j = 0; j < 4; ++j) {
                int row = wn + j * 16 + fr;
                bf[j] = *(const bf16x8*)(Bs + row * 64 + (((s * 4 + fq) ^ (row & 7)) * 8));
            }
            #pragma unroll
            for (int i = 0; i < 2; ++i)
                #pragma unroll
                for (int j = 0; j < 4; ++j)
                    acc[i][j] = __builtin_amdgcn_mfma_f32_16x16x32_bf16(af[i], bf[j], acc[i][j], 0, 0, 0);
        }
        __syncthreads();
    }

    const int cr = (lane >> 4) * 4;
    const int cc = lane & 15;
    #pragma unroll
    for (int j = 0; j < 4; ++j) {
        int col = bn + wn + j * 16 + cc;
        if (kchunks == 1) {
            float bb = bias ? bias[col] : 0.f;
            #pragma unroll
            for (int i = 0; i < 2; ++i)
                #pragma unroll
                for (int r = 0; r < 4; ++r)
                    C[(size_t)(bm + wm + i * 16 + cr + r) * N + col] = acc[i][j][r] + bb;
        } else {
            #pragma unroll
            for (int i = 0; i < 2; ++i)
                #pragma unroll
                for (int r = 0; r < 4; ++r)
                    atomicAdd(C + (size_t)(bm + wm + i * 16 + cr + r) * N + col, acc[i][j][r]);
        }
    }
}

// ---------------------------------------------------------------------------
// FUSED output GEMMs (fence-free union, verified): id<512 -> out =
// W_sp @ Vo + bo; id>=512 -> Y = W_dn @ X (split-K x2, atomics).
// ---------------------------------------------------------------------------
__global__ void __launch_bounds__(256) gemm_bt2x(
    const __bf16* __restrict__ Wsp, const __bf16* __restrict__ VoT,
    const float* __restrict__ bo, float* __restrict__ out,
    const __bf16* __restrict__ WdT, const __bf16* __restrict__ xbT,
    float* __restrict__ Y)
{
    __shared__ __bf16 As[64 * 64];
    __shared__ __bf16 Bs[128 * 64];
    const int t = threadIdx.x;
    int id = blockIdx.x;
    if (id < 512) {
        int bx = id & 7, by = (id >> 3) & 31, bz = id >> 8;
        gemm_bt_body(As, Bs,
                     Wsp + (size_t)bz * 2048 * 256, VoT + (size_t)bz * 1024 * 256,
                     bo, out + (size_t)bz * 2048 * 1024,
                     1024, 256, by * 64, bx * 128, 0, 1, t);
    } else {
        id -= 512;
        int bx = id & 7, by = (id >> 3) & 3, z = id >> 5;   // z in 0..3
        int batch = z >> 1, kc = z & 1;
        gemm_bt_body(As, Bs,
                     WdT + (size_t)batch * 256 * 2048, xbT + (size_t)batch * 1024 * 2048,
                     nullptr, Y + (size_t)batch * 256 * 1024,
                     1024, 2048, by * 64, bx * 128, kc, 2, t);
    }
}

// ---------------------------------------------------------------------------
// Dense finalize A (split-K, 256 blocks): zbuf (init bv) += Y @ Wv chunk.
// Grid (16 h, 8 kc, 2 b).
// ---------------------------------------------------------------------------
__global__ void __launch_bounds__(256) dense_z2(
    const float* __restrict__ Y, const float* __restrict__ Wv,
    float* __restrict__ zbuf)
{
    const int h = blockIdx.x, kc = blockIdx.y, b = blockIdx.z;
    const int t = threadIdx.x;
    __shared__ float Ys[16][128];
    const int k0 = kc * 128;
    #pragma unroll
    for (int l = 0; l < 2; ++l) {
        int c = l * 256 + t;
        int row = c >> 5, c4 = c & 31;
        *(float4*)&Ys[row][c4 * 4] =
            *(const float4*)(Y + ((size_t)(b * 256 + h * 16 + row)) * 1024 + k0 + c4 * 4);
    }
    __syncthreads();
    const int d = t & 63, tg = t >> 6;
    float acc[4] = {};
    #pragma unroll 8
    for (int kk = 0; kk < 128; ++kk) {
        float wv = Wv[(size_t)(k0 + kk) * 1024 + h * 64 + d];
        #pragma unroll
        for (int tt = 0; tt < 4; ++tt)
            acc[tt] = fmaf(Ys[tg * 4 + tt][kk], wv, acc[tt]);
    }
    #pragma unroll
    for (int tt = 0; tt < 4; ++tt)
        atomicAdd(zbuf + ((size_t)(b * 16 + tg * 4 + tt)) * 1024 + h * 64 + d, acc[tt]);
}

// ---------------------------------------------------------------------------
// Dense finalize B (split-K, 256 blocks): obuf (init bo) += z @ Wo chunk.
// Grid (16 ntiles of 64, 8 kc, 2 b). NO trailing fence/scatter.
// ---------------------------------------------------------------------------
__global__ void __launch_bounds__(256) dense_out2(
    const float* __restrict__ zbuf, const float* __restrict__ Wo,
    float* __restrict__ obuf)
{
    const int nt = blockIdx.x, kc = blockIdx.y, b = blockIdx.z;
    const int t = threadIdx.x;
    __shared__ float zs[16][128];
    const int k0 = kc * 128;
    #pragma unroll
    for (int l = 0; l < 2; ++l) {
        int c = l * 256 + t;
        int row = c >> 5, c4 = c & 31;
        *(float4*)&zs[row][c4 * 4] =
            *(const float4*)(zbuf + ((size_t)(b * 16 + row)) * 1024 + k0 + c4 * 4);
    }
    __syncthreads();
    const int n = nt * 64 + (t & 63), tg = t >> 6;
    float acc[4] = {};
    #pragma unroll 8
    for (int kk = 0; kk < 128; ++kk) {
        float wv = Wo[(size_t)(k0 + kk) * 1024 + n];
        #pragma unroll
        for (int tt = 0; tt < 4; ++tt)
            acc[tt] = fmaf(zs[tg * 4 + tt][kk], wv, acc[tt]);
    }
    #pragma unroll
    for (int tt = 0; tt < 4; ++tt)
        atomicAdd(obuf + ((size_t)(b * 16 + tg * 4 + tt)) * 1024 + n, acc[tt]);
}

// ---------------------------------------------------------------------------
// Scatter dense rows: out[sel[t]] = obuf[t]. Grid 32.
// ---------------------------------------------------------------------------
__global__ void __launch_bounds__(256) scatter_out(
    const float* __restrict__ obuf, const int* __restrict__ sel_idx,
    float* __restrict__ out)
{
    const int bid = blockIdx.x;
    const int b = bid >> 4, row = bid & 15;
    const int i = sel_idx[b * 16 + row];
    f32x4 v = *(const f32x4*)(obuf + ((size_t)(b * 16 + row)) * 1024 + threadIdx.x * 4);
    *(f32x4*)(out + ((size_t)(b * 2048 + i)) * 1024 + threadIdx.x * 4) = v;
}

// ---------------------------------------------------------------------------
extern "C" void kernel_launch(void* const* d_in, const int* in_sizes, int n_in,
                              void* d_out, int out_size, void* d_ws, size_t ws_size,
                              hipStream_t stream)
{
    const float* x   = (const float*)d_in[0];
    const float* Wq  = (const float*)d_in[1];
    const float* bq  = (const float*)d_in[2];
    const float* Wk  = (const float*)d_in[3];
    const float* bk  = (const float*)d_in[4];
    const float* Wv  = (const float*)d_in[5];
    const float* bv  = (const float*)d_in[6];
    const float* Wo  = (const float*)d_in[7];
    const float* bo  = (const float*)d_in[8];
    const float* Ws1 = (const float*)d_in[9];
    const float* bs1 = (const float*)d_in[10];
    const float* Ws2 = (const float*)d_in[11];
    float* out = (float*)d_out;

    const size_t MSD = (size_t)Bb * Ss * Dd;   // 4,194,304

    char* p = (char*)d_ws;
    __bf16* xb    = (__bf16*)p; p += MSD * sizeof(__bf16);
    __bf16* xbT   = (__bf16*)p; p += MSD * sizeof(__bf16);
    __bf16* W1Th  = (__bf16*)p; p += (size_t)512 * 1024 * sizeof(__bf16);
    __bf16* ET    = (__bf16*)p; p += (size_t)2 * 512 * 1024 * sizeof(__bf16);
    __bf16* VoT   = (__bf16*)p; p += (size_t)2 * 1024 * 256 * sizeof(__bf16);
    __bf16* Wsp   = (__bf16*)p; p += (size_t)2 * 2048 * 256 * sizeof(__bf16);
    __bf16* WdT   = (__bf16*)p; p += (size_t)2 * 256 * 2048 * sizeof(__bf16);
    float* Ssp    = (float*)p; p += (size_t)2 * 2048 * 256 * sizeof(float);
    float* SdT    = (float*)p; p += (size_t)2 * 256 * 2048 * sizeof(float);
    float* Y      = (float*)p; p += (size_t)2 * 256 * 1024 * sizeof(float);
    float* zbuf   = (float*)p; p += (size_t)2 * 16 * 1024 * sizeof(float);
    float* obuf   = (float*)p; p += (size_t)2 * 16 * 1024 * sizeof(float);
    float* imp    = (float*)p; p += (size_t)Bb * Ss * sizeof(float);
    float* hbuf   = (float*)p; p += (size_t)Bb * 64 * 512 * sizeof(float);
    float* qkvsel = (float*)p; p += (size_t)3 * 32 * 1024 * sizeof(float);
    float* beta   = (float*)p; p += (size_t)2 * 256 * sizeof(float);
    int* sel_idx  = (int*)p; p += (size_t)Bb * Kk * sizeof(int);
    int* cand_idx = (int*)p; p += (size_t)Bb * 64 * sizeof(int);
    int* ccount   = (int*)p; p += Bb * sizeof(int);

    // 1) prep: inits (1024) + transpose&pack x once (4096) + Ws1 T (512).
    prep_kernel<<<dim3(5632), 256, 0, stream>>>(
        x, xb, xbT, imp, hbuf, qkvsel, ccount, Ws1, W1Th,
        bv, bo, Y, zbuf, obuf);
    // 2) approximate indexer GEMM -> imp (256 blocks, fence-free).
    gemm_ind<<<dim3(4, 64), 256, 0, stream>>>(xb, W1Th, bs1, Ws2, imp);
    // 3) fast candidate generation (single-wave argmax).
    topk_fast<<<dim3(Bb), 256, 0, stream>>>(imp, cand_idx, ccount);
    // 4) exact rescore: parallel partial-h, then fused finalize+selection.
    rescore_h<<<dim3(64, 16, Bb), 256, 0, stream>>>(x, Ws1, cand_idx, ccount, hbuf);
    rescore_fin_sel<<<dim3(Bb), 256, 0, stream>>>(
        hbuf, bs1, Ws2, cand_idx, ccount, sel_idx);
    // 5) exact f32 projections of the 32 selected rows.
    proj_sel<<<dim3(8, 3, 8), 256, 0, stream>>>(x, Wq, Wk, Wv, sel_idx, qkvsel);
    // 6) build algebraic operands C, D (-> ET), Vo^T, beta.
    build_cdvo<<<dim3(8, 16, 2), 256, 0, stream>>>(
        Wq, Wk, Wo, bq, bk, bv, qkvsel, beta, ET, VoT);
    // 7) all scores in one GEMM: S = X @ [C|D] (256 blocks).
    gemm_scores<<<dim3(4, 32, 2), 256, 0, stream>>>(xb, ET, Ssp, SdT);
    // 8) FUSED softmaxes -> bf16 weight matrices.
    sm_all<<<dim3(768, 2), 256, 0, stream>>>(Ssp, beta, Wsp, SdT, WdT);
    // 9) FUSED output GEMMs: sparse out (512 blocks) + Y = W_dn @ X (128).
    gemm_bt2x<<<dim3(640), 256, 0, stream>>>(Wsp, VoT, bo, out, WdT, xbT, Y);
    // 10) dense tail: zbuf(+=bv) = Y@Wv; obuf(+=bo) = z@Wo; scatter.
    dense_z2<<<dim3(16, 8, 2), 256, 0, stream>>>(Y, Wv, zbuf);
    dense_out2<<<dim3(16, 8, 2), 256, 0, stream>>>(zbuf, Wo, obuf);
    scatter_out<<<dim3(32), 256, 0, stream>>>(obuf, sel_idx, out);
}